// Round 5
// baseline (1339.093 us; speedup 1.0000x reference)
//
#include <hip/hip_runtime.h>
#include <math.h>

#define NN 50000
#define NE 800000
#define D  128
#define SCAN_CHUNK 1024
#define NSCAN ((NN + SCAN_CHUNK - 1) / SCAN_CHUNK)   // 49

// ---------------- in-degree histogram (dst), int4-vectorized ----------------
__global__ __launch_bounds__(320) void k_deg(const int* __restrict__ ei,
                                             int* __restrict__ deg) {
    int t = blockIdx.x * 320 + threadIdx.x;       // 625 blocks * 320 * 4 = NE
    int4 d4 = ((const int4*)(ei + NE))[t];
    atomicAdd(&deg[d4.x], 1);
    atomicAdd(&deg[d4.y], 1);
    atomicAdd(&deg[d4.z], 1);
    atomicAdd(&deg[d4.w], 1);
}

// ---------------- scan stage A: per-chunk sums + dinv ----------------
__global__ __launch_bounds__(256) void k_scan_a(const int* __restrict__ deg,
                                                int* __restrict__ partial,
                                                float* __restrict__ dinv) {
    __shared__ int red[256];
    int t = threadIdx.x;
    int base = blockIdx.x * SCAN_CHUNK + t * 4;
    int s = 0;
#pragma unroll
    for (int j = 0; j < 4; j++) {
        int i = base + j;
        if (i < NN) {
            int d = deg[i];
            s += d;
            dinv[i] = rsqrtf((float)d + 1.0f);   // +1 self loop
        }
    }
    red[t] = s; __syncthreads();
#pragma unroll
    for (int off = 128; off > 0; off >>= 1) {
        if (t < off) red[t] += red[t + off];
        __syncthreads();
    }
    if (t == 0) partial[blockIdx.x] = red[0];
}

// ---------------- scan stage C: block prefix via shuffle + chunk scan --------
__global__ __launch_bounds__(256) void k_scan_c(const int* __restrict__ deg,
                                                const int* __restrict__ partial,
                                                int* __restrict__ rowoff,
                                                int* __restrict__ cur) {
    __shared__ int sbuf[256];
    int t = threadIdx.x;
    int lane = t & 63;
    int pv = (lane < NSCAN && lane < (int)blockIdx.x) ? partial[lane] : 0;
#pragma unroll
    for (int off = 32; off > 0; off >>= 1) pv += __shfl_xor(pv, off, 64);

    int base = blockIdx.x * SCAN_CHUNK + t * 4;
    int d[4]; int s = 0;
#pragma unroll
    for (int j = 0; j < 4; j++) {
        d[j] = (base + j < NN) ? deg[base + j] : 0;
        s += d[j];
    }
    sbuf[t] = s; __syncthreads();
    for (int off = 1; off < 256; off <<= 1) {
        int v = (t >= off) ? sbuf[t - off] : 0;
        __syncthreads();
        sbuf[t] += v;
        __syncthreads();
    }
    int ex = sbuf[t] - s + pv;
#pragma unroll
    for (int j = 0; j < 4; j++) {
        int i = base + j;
        if (i < NN) {
            rowoff[i] = ex; cur[i] = ex;
            ex += d[j];
            if (i == NN - 1) rowoff[NN] = ex;   // sentinel = NE
        }
    }
}

// ---------------- CSR fill (counting-sort placement), int4 ----------------
__global__ __launch_bounds__(320) void k_fill(const int* __restrict__ ei,
                                              int* __restrict__ cur,
                                              int* __restrict__ csr) {
    int t = blockIdx.x * 320 + threadIdx.x;
    int4 s4 = ((const int4*)ei)[t];
    int4 d4 = ((const int4*)(ei + NE))[t];
    csr[atomicAdd(&cur[d4.x], 1)] = s4.x;
    csr[atomicAdd(&cur[d4.y], 1)] = s4.y;
    csr[atomicAdd(&cur[d4.z], 1)] = s4.z;
    csr[atomicAdd(&cur[d4.w], 1)] = s4.w;
}

// ---------------- fused: gather + GEMM + bias + LN + tanh (NO LDS) ----------
// Block 256 = 4 independent waves; each wave owns 4 rows (16 rows/block,
// grid = 3125 exactly). Lane owns cols (2*lane, 2*lane+1).
// Edge loop manually unrolled x4 for memory-level parallelism.
__global__ __launch_bounds__(256) void k_main(
        const int* __restrict__ rowoff, const int* __restrict__ csr,
        const float* __restrict__ dinv, const float* __restrict__ h,
        const float* __restrict__ Wg,   const float* __restrict__ bias,
        const float* __restrict__ gamma,const float* __restrict__ beta,
        float* __restrict__ out) {
    int tid = threadIdx.x;
    int w = tid >> 6, lane = tid & 63;
    int rowBase = blockIdx.x * 16 + w * 4;
    const float2* h2 = (const float2*)h;
    const float2* W2 = (const float2*)Wg;

    // ---- gather into registers: x[r] = dn*(dn*h[row] + sum dinv[s]*h[s]) ----
    float2 x[4];
    for (int r = 0; r < 4; r++) {
        int row = rowBase + r;
        float dn = dinv[row];
        float2 hv = h2[(size_t)row * 64 + lane];
        float2 a;
        a.x = dn * hv.x; a.y = dn * hv.y;
        int start = rowoff[row], end = rowoff[row + 1];
        for (int c = start; c < end; c += 64) {
            int m = end - c; if (m > 64) m = 64;
            int s = 0; float wv = 0.f;
            if (lane < m) { s = csr[c + lane]; wv = dinv[s]; }
            int j = 0;
            for (; j + 3 < m; j += 4) {
                int   sa = __shfl(s,  j, 64),     sb = __shfl(s,  j + 1, 64);
                int   sc = __shfl(s,  j + 2, 64), sd = __shfl(s,  j + 3, 64);
                float wa = __shfl(wv, j, 64),     wb = __shfl(wv, j + 1, 64);
                float wc = __shfl(wv, j + 2, 64), wd = __shfl(wv, j + 3, 64);
                float2 ha = h2[(size_t)sa * 64 + lane];
                float2 hb = h2[(size_t)sb * 64 + lane];
                float2 hc = h2[(size_t)sc * 64 + lane];
                float2 hd = h2[(size_t)sd * 64 + lane];
                a.x = fmaf(wa, ha.x, a.x);  a.y = fmaf(wa, ha.y, a.y);
                a.x = fmaf(wb, hb.x, a.x);  a.y = fmaf(wb, hb.y, a.y);
                a.x = fmaf(wc, hc.x, a.x);  a.y = fmaf(wc, hc.y, a.y);
                a.x = fmaf(wd, hd.x, a.x);  a.y = fmaf(wd, hd.y, a.y);
            }
            for (; j < m; j++) {
                int   sj = __shfl(s,  j, 64);
                float wj = __shfl(wv, j, 64);
                float2 hj = h2[(size_t)sj * 64 + lane];
                a.x = fmaf(wj, hj.x, a.x);
                a.y = fmaf(wj, hj.y, a.y);
            }
        }
        a.x *= dn; a.y *= dn;
        x[r] = a;
    }

    // ---- GEMM via register broadcast: y[c] = sum_k x[k] * W[k][c] ----
    float2 acc[4];
#pragma unroll
    for (int r = 0; r < 4; r++) acc[r] = make_float2(0.f, 0.f);

    // even k = 2j: x[2j] lives in lane j's .x
#pragma unroll
    for (int j = 0; j < 64; j++) {
        float2 wv = W2[(size_t)(2 * j) * 64 + lane];
#pragma unroll
        for (int r = 0; r < 4; r++) {
            float xk = __shfl(x[r].x, j, 64);
            acc[r].x = fmaf(xk, wv.x, acc[r].x);
            acc[r].y = fmaf(xk, wv.y, acc[r].y);
        }
    }
    // odd k = 2j+1: x[2j+1] lives in lane j's .y
#pragma unroll
    for (int j = 0; j < 64; j++) {
        float2 wv = W2[(size_t)(2 * j + 1) * 64 + lane];
#pragma unroll
        for (int r = 0; r < 4; r++) {
            float xk = __shfl(x[r].y, j, 64);
            acc[r].x = fmaf(xk, wv.x, acc[r].x);
            acc[r].y = fmaf(xk, wv.y, acc[r].y);
        }
    }

    // ---- bias + LN + tanh + store ----
    float2 bi = ((const float2*)bias)[lane];
    float2 ga = ((const float2*)gamma)[lane];
    float2 be = ((const float2*)beta)[lane];
#pragma unroll
    for (int r = 0; r < 4; r++) {
        int row = rowBase + r;
        float y0 = acc[r].x + bi.x;
        float y1 = acc[r].y + bi.y;
        float s = y0 + y1;
#pragma unroll
        for (int off = 32; off > 0; off >>= 1) s += __shfl_xor(s, off, 64);
        float m = s * (1.0f / 128.0f);
        float v0 = y0 - m, v1 = y1 - m;
        float vs = v0 * v0 + v1 * v1;
#pragma unroll
        for (int off = 32; off > 0; off >>= 1) vs += __shfl_xor(vs, off, 64);
        float rstd = rsqrtf(vs * (1.0f / 128.0f) + 1e-5f);
        float2 o;
        o.x = tanhf(v0 * rstd * ga.x + be.x);
        o.y = tanhf(v1 * rstd * ga.y + be.y);
        *(float2*)&out[(size_t)row * D + lane * 2] = o;
    }
}

extern "C" void kernel_launch(void* const* d_in, const int* in_sizes, int n_in,
                              void* d_out, int out_size, void* d_ws, size_t ws_size,
                              hipStream_t stream) {
    // inputs: t, h, edge_index, batch_size, W, b, gamma, beta
    const float* h     = (const float*)d_in[1];
    const int*   ei    = (const int*)  d_in[2];
    const float* Wg    = (const float*)d_in[4];
    const float* b     = (const float*)d_in[5];
    const float* gamma = (const float*)d_in[6];
    const float* beta  = (const float*)d_in[7];
    float* out = (float*)d_out;

    // workspace layout
    int*   deg    = (int*)d_ws;                 // NN
    int*   cur    = deg + NN;                   // NN
    int*   rowoff = cur + NN;                   // NN + 1
    float* dinv   = (float*)(rowoff + NN + 1);  // NN
    int*   partial= (int*)(dinv + NN);          // 64
    int*   csr    = partial + 64;               // NE

    hipMemsetAsync(deg, 0, NN * sizeof(int), stream);
    // zero tail outputs (zeros_like(edge_index) + zeros_like(batch_size))
    size_t dh_bytes  = (size_t)NN * D * sizeof(float);
    size_t out_bytes = (size_t)out_size * sizeof(float);
    if (out_bytes > dh_bytes)
        hipMemsetAsync((char*)d_out + dh_bytes, 0, out_bytes - dh_bytes, stream);

    k_deg   <<<625,   320, 0, stream>>>(ei, deg);
    k_scan_a<<<NSCAN, 256, 0, stream>>>(deg, partial, dinv);
    k_scan_c<<<NSCAN, 256, 0, stream>>>(deg, partial, rowoff, cur);
    k_fill  <<<625,   320, 0, stream>>>(ei, cur, csr);
    k_main  <<<NN / 16, 256, 0, stream>>>(rowoff, csr, dinv, h, Wg, b, gamma, beta, out);
}

// Round 6
// 297.098 us; speedup vs baseline: 4.5072x; 4.5072x over previous
//
#include <hip/hip_runtime.h>
#include <math.h>

#define NN 50000
#define NE 800000
#define D  128
#define SCAN_CHUNK 1024
#define NSCAN ((NN + SCAN_CHUNK - 1) / SCAN_CHUNK)   // 49

// ---------------- in-degree histogram (dst), int4-vectorized ----------------
__global__ __launch_bounds__(320) void k_deg(const int* __restrict__ ei,
                                             int* __restrict__ deg) {
    int t = blockIdx.x * 320 + threadIdx.x;       // 625 blocks * 320 * 4 = NE
    int4 d4 = ((const int4*)(ei + NE))[t];
    atomicAdd(&deg[d4.x], 1);
    atomicAdd(&deg[d4.y], 1);
    atomicAdd(&deg[d4.z], 1);
    atomicAdd(&deg[d4.w], 1);
}

// ---------------- scan stage A: per-chunk sums + dinv ----------------
__global__ __launch_bounds__(256) void k_scan_a(const int* __restrict__ deg,
                                                int* __restrict__ partial,
                                                float* __restrict__ dinv) {
    __shared__ int red[256];
    int t = threadIdx.x;
    int base = blockIdx.x * SCAN_CHUNK + t * 4;
    int s = 0;
#pragma unroll
    for (int j = 0; j < 4; j++) {
        int i = base + j;
        if (i < NN) {
            int d = deg[i];
            s += d;
            dinv[i] = rsqrtf((float)d + 1.0f);   // +1 self loop
        }
    }
    red[t] = s; __syncthreads();
#pragma unroll
    for (int off = 128; off > 0; off >>= 1) {
        if (t < off) red[t] += red[t + off];
        __syncthreads();
    }
    if (t == 0) partial[blockIdx.x] = red[0];
}

// ---------------- scan stage C: block prefix via shuffle + chunk scan --------
__global__ __launch_bounds__(256) void k_scan_c(const int* __restrict__ deg,
                                                const int* __restrict__ partial,
                                                int* __restrict__ rowoff,
                                                int* __restrict__ cur) {
    __shared__ int sbuf[256];
    int t = threadIdx.x;
    int lane = t & 63;
    int pv = (lane < NSCAN && lane < (int)blockIdx.x) ? partial[lane] : 0;
#pragma unroll
    for (int off = 32; off > 0; off >>= 1) pv += __shfl_xor(pv, off, 64);

    int base = blockIdx.x * SCAN_CHUNK + t * 4;
    int d[4]; int s = 0;
#pragma unroll
    for (int j = 0; j < 4; j++) {
        d[j] = (base + j < NN) ? deg[base + j] : 0;
        s += d[j];
    }
    sbuf[t] = s; __syncthreads();
    for (int off = 1; off < 256; off <<= 1) {
        int v = (t >= off) ? sbuf[t - off] : 0;
        __syncthreads();
        sbuf[t] += v;
        __syncthreads();
    }
    int ex = sbuf[t] - s + pv;
#pragma unroll
    for (int j = 0; j < 4; j++) {
        int i = base + j;
        if (i < NN) {
            rowoff[i] = ex; cur[i] = ex;
            ex += d[j];
            if (i == NN - 1) rowoff[NN] = ex;   // sentinel = NE
        }
    }
}

// ---------------- CSR fill (counting-sort placement), int4 ----------------
__global__ __launch_bounds__(320) void k_fill(const int* __restrict__ ei,
                                              int* __restrict__ cur,
                                              int* __restrict__ csr) {
    int t = blockIdx.x * 320 + threadIdx.x;
    int4 s4 = ((const int4*)ei)[t];
    int4 d4 = ((const int4*)(ei + NE))[t];
    csr[atomicAdd(&cur[d4.x], 1)] = s4.x;
    csr[atomicAdd(&cur[d4.y], 1)] = s4.y;
    csr[atomicAdd(&cur[d4.z], 1)] = s4.z;
    csr[atomicAdd(&cur[d4.w], 1)] = s4.w;
}

// ---------------- fused: gather + GEMM + bias + LN + tanh (NO LDS) ----------
// Block 256 = 4 independent waves; each wave owns 4 rows (16 rows/block,
// grid = 3125 exactly). Lane owns cols (2*lane, 2*lane+1).
// Edge loop manually unrolled x4 for MLP; GEMM loops unroll-capped at 4 to
// keep VGPR ~48 (full unroll spilled to scratch: R4 postmortem, 2.5GB/launch).
__global__ __launch_bounds__(256) void k_main(
        const int* __restrict__ rowoff, const int* __restrict__ csr,
        const float* __restrict__ dinv, const float* __restrict__ h,
        const float* __restrict__ Wg,   const float* __restrict__ bias,
        const float* __restrict__ gamma,const float* __restrict__ beta,
        float* __restrict__ out) {
    int tid = threadIdx.x;
    int w = tid >> 6, lane = tid & 63;
    int rowBase = blockIdx.x * 16 + w * 4;
    const float2* h2 = (const float2*)h;
    const float2* W2 = (const float2*)Wg;

    // ---- gather into registers: x[r] = dn*(dn*h[row] + sum dinv[s]*h[s]) ----
    float2 x[4];
    for (int r = 0; r < 4; r++) {
        int row = rowBase + r;
        float dn = dinv[row];
        float2 hv = h2[(size_t)row * 64 + lane];
        float2 a;
        a.x = dn * hv.x; a.y = dn * hv.y;
        int start = rowoff[row], end = rowoff[row + 1];
        for (int c = start; c < end; c += 64) {
            int m = end - c; if (m > 64) m = 64;
            int s = 0; float wv = 0.f;
            if (lane < m) { s = csr[c + lane]; wv = dinv[s]; }
            int j = 0;
            for (; j + 3 < m; j += 4) {
                int   sa = __shfl(s,  j, 64),     sb = __shfl(s,  j + 1, 64);
                int   sc = __shfl(s,  j + 2, 64), sd = __shfl(s,  j + 3, 64);
                float wa = __shfl(wv, j, 64),     wb = __shfl(wv, j + 1, 64);
                float wc = __shfl(wv, j + 2, 64), wd = __shfl(wv, j + 3, 64);
                float2 ha = h2[(size_t)sa * 64 + lane];
                float2 hb = h2[(size_t)sb * 64 + lane];
                float2 hc = h2[(size_t)sc * 64 + lane];
                float2 hd = h2[(size_t)sd * 64 + lane];
                a.x = fmaf(wa, ha.x, a.x);  a.y = fmaf(wa, ha.y, a.y);
                a.x = fmaf(wb, hb.x, a.x);  a.y = fmaf(wb, hb.y, a.y);
                a.x = fmaf(wc, hc.x, a.x);  a.y = fmaf(wc, hc.y, a.y);
                a.x = fmaf(wd, hd.x, a.x);  a.y = fmaf(wd, hd.y, a.y);
            }
            for (; j < m; j++) {
                int   sj = __shfl(s,  j, 64);
                float wj = __shfl(wv, j, 64);
                float2 hj = h2[(size_t)sj * 64 + lane];
                a.x = fmaf(wj, hj.x, a.x);
                a.y = fmaf(wj, hj.y, a.y);
            }
        }
        a.x *= dn; a.y *= dn;
        x[r] = a;
    }

    // ---- GEMM via register broadcast: y[c] = sum_k x[k] * W[k][c] ----
    float2 acc[4];
#pragma unroll
    for (int r = 0; r < 4; r++) acc[r] = make_float2(0.f, 0.f);

    // even k = 2j: x[2j] lives in lane j's .x
#pragma unroll 4
    for (int j = 0; j < 64; j++) {
        float2 wv = W2[(size_t)(2 * j) * 64 + lane];
#pragma unroll
        for (int r = 0; r < 4; r++) {
            float xk = __shfl(x[r].x, j, 64);
            acc[r].x = fmaf(xk, wv.x, acc[r].x);
            acc[r].y = fmaf(xk, wv.y, acc[r].y);
        }
    }
    // odd k = 2j+1: x[2j+1] lives in lane j's .y
#pragma unroll 4
    for (int j = 0; j < 64; j++) {
        float2 wv = W2[(size_t)(2 * j + 1) * 64 + lane];
#pragma unroll
        for (int r = 0; r < 4; r++) {
            float xk = __shfl(x[r].y, j, 64);
            acc[r].x = fmaf(xk, wv.x, acc[r].x);
            acc[r].y = fmaf(xk, wv.y, acc[r].y);
        }
    }

    // ---- bias + LN + tanh + store ----
    float2 bi = ((const float2*)bias)[lane];
    float2 ga = ((const float2*)gamma)[lane];
    float2 be = ((const float2*)beta)[lane];
#pragma unroll
    for (int r = 0; r < 4; r++) {
        int row = rowBase + r;
        float y0 = acc[r].x + bi.x;
        float y1 = acc[r].y + bi.y;
        float s = y0 + y1;
#pragma unroll
        for (int off = 32; off > 0; off >>= 1) s += __shfl_xor(s, off, 64);
        float m = s * (1.0f / 128.0f);
        float v0 = y0 - m, v1 = y1 - m;
        float vs = v0 * v0 + v1 * v1;
#pragma unroll
        for (int off = 32; off > 0; off >>= 1) vs += __shfl_xor(vs, off, 64);
        float rstd = rsqrtf(vs * (1.0f / 128.0f) + 1e-5f);
        float2 o;
        o.x = tanhf(v0 * rstd * ga.x + be.x);
        o.y = tanhf(v1 * rstd * ga.y + be.y);
        *(float2*)&out[(size_t)row * D + lane * 2] = o;
    }
}

extern "C" void kernel_launch(void* const* d_in, const int* in_sizes, int n_in,
                              void* d_out, int out_size, void* d_ws, size_t ws_size,
                              hipStream_t stream) {
    // inputs: t, h, edge_index, batch_size, W, b, gamma, beta
    const float* h     = (const float*)d_in[1];
    const int*   ei    = (const int*)  d_in[2];
    const float* Wg    = (const float*)d_in[4];
    const float* b     = (const float*)d_in[5];
    const float* gamma = (const float*)d_in[6];
    const float* beta  = (const float*)d_in[7];
    float* out = (float*)d_out;

    // workspace layout
    int*   deg    = (int*)d_ws;                 // NN
    int*   cur    = deg + NN;                   // NN
    int*   rowoff = cur + NN;                   // NN + 1
    float* dinv   = (float*)(rowoff + NN + 1);  // NN
    int*   partial= (int*)(dinv + NN);          // 64
    int*   csr    = partial + 64;               // NE

    hipMemsetAsync(deg, 0, NN * sizeof(int), stream);
    // zero tail outputs (zeros_like(edge_index) + zeros_like(batch_size))
    size_t dh_bytes  = (size_t)NN * D * sizeof(float);
    size_t out_bytes = (size_t)out_size * sizeof(float);
    if (out_bytes > dh_bytes)
        hipMemsetAsync((char*)d_out + dh_bytes, 0, out_bytes - dh_bytes, stream);

    k_deg   <<<625,   320, 0, stream>>>(ei, deg);
    k_scan_a<<<NSCAN, 256, 0, stream>>>(deg, partial, dinv);
    k_scan_c<<<NSCAN, 256, 0, stream>>>(deg, partial, rowoff, cur);
    k_fill  <<<625,   320, 0, stream>>>(ei, cur, csr);
    k_main  <<<NN / 16, 256, 0, stream>>>(rowoff, csr, dinv, h, Wg, b, gamma, beta, out);
}

// Round 7
// 267.437 us; speedup vs baseline: 5.0071x; 1.1109x over previous
//
#include <hip/hip_runtime.h>
#include <math.h>

#define NN 50000
#define NE 800000
#define D  128
#define SCAN_CHUNK 1024
#define NSCAN ((NN + SCAN_CHUNK - 1) / SCAN_CHUNK)   // 49

// ---- in-degree histogram (dst) + per-edge rank (atomic return), int4 ----
__global__ __launch_bounds__(320) void k_deg(const int* __restrict__ ei,
                                             int* __restrict__ deg,
                                             unsigned short* __restrict__ rank) {
    int t = blockIdx.x * 320 + threadIdx.x;       // 625 blocks * 320 * 4 = NE
    int4 d4 = ((const int4*)(ei + NE))[t];
    ushort4 r;
    r.x = (unsigned short)atomicAdd(&deg[d4.x], 1);
    r.y = (unsigned short)atomicAdd(&deg[d4.y], 1);
    r.z = (unsigned short)atomicAdd(&deg[d4.z], 1);
    r.w = (unsigned short)atomicAdd(&deg[d4.w], 1);
    ((ushort4*)rank)[t] = r;
}

// ---- h fp32 -> packed bf16x2 (RNE), for the gather phase ----
__global__ __launch_bounds__(256) void k_cvt(const float* __restrict__ h,
                                             unsigned* __restrict__ hb) {
    int t = blockIdx.x * 256 + threadIdx.x;       // grid = NN*64/256 = 12500
    float2 v = ((const float2*)h)[t];
    unsigned a = __float_as_uint(v.x);
    unsigned b = __float_as_uint(v.y);
    a = a + 0x7FFFu + ((a >> 16) & 1u);           // round-to-nearest-even
    b = b + 0x7FFFu + ((b >> 16) & 1u);
    hb[t] = (a >> 16) | (b & 0xFFFF0000u);
}

// ---------------- scan stage A: per-chunk sums + dinv ----------------
__global__ __launch_bounds__(256) void k_scan_a(const int* __restrict__ deg,
                                                int* __restrict__ partial,
                                                float* __restrict__ dinv) {
    __shared__ int red[256];
    int t = threadIdx.x;
    int base = blockIdx.x * SCAN_CHUNK + t * 4;
    int s = 0;
#pragma unroll
    for (int j = 0; j < 4; j++) {
        int i = base + j;
        if (i < NN) {
            int d = deg[i];
            s += d;
            dinv[i] = rsqrtf((float)d + 1.0f);   // +1 self loop
        }
    }
    red[t] = s; __syncthreads();
#pragma unroll
    for (int off = 128; off > 0; off >>= 1) {
        if (t < off) red[t] += red[t + off];
        __syncthreads();
    }
    if (t == 0) partial[blockIdx.x] = red[0];
}

// ---------------- scan stage C: block prefix via shuffle + chunk scan --------
__global__ __launch_bounds__(256) void k_scan_c(const int* __restrict__ deg,
                                                const int* __restrict__ partial,
                                                int* __restrict__ rowoff) {
    __shared__ int sbuf[256];
    int t = threadIdx.x;
    int lane = t & 63;
    int pv = (lane < NSCAN && lane < (int)blockIdx.x) ? partial[lane] : 0;
#pragma unroll
    for (int off = 32; off > 0; off >>= 1) pv += __shfl_xor(pv, off, 64);

    int base = blockIdx.x * SCAN_CHUNK + t * 4;
    int d[4]; int s = 0;
#pragma unroll
    for (int j = 0; j < 4; j++) {
        d[j] = (base + j < NN) ? deg[base + j] : 0;
        s += d[j];
    }
    sbuf[t] = s; __syncthreads();
    for (int off = 1; off < 256; off <<= 1) {
        int v = (t >= off) ? sbuf[t - off] : 0;
        __syncthreads();
        sbuf[t] += v;
        __syncthreads();
    }
    int ex = sbuf[t] - s + pv;
#pragma unroll
    for (int j = 0; j < 4; j++) {
        int i = base + j;
        if (i < NN) {
            rowoff[i] = ex;
            ex += d[j];
            if (i == NN - 1) rowoff[NN] = ex;   // sentinel = NE
        }
    }
}

// ---------------- CSR fill: NO atomics (uses precomputed rank) ----------------
__global__ __launch_bounds__(320) void k_fill(const int* __restrict__ ei,
                                              const int* __restrict__ rowoff,
                                              const unsigned short* __restrict__ rank,
                                              int* __restrict__ csr) {
    int t = blockIdx.x * 320 + threadIdx.x;
    int4 s4 = ((const int4*)ei)[t];
    int4 d4 = ((const int4*)(ei + NE))[t];
    ushort4 r4 = ((const ushort4*)rank)[t];
    csr[rowoff[d4.x] + r4.x] = s4.x;
    csr[rowoff[d4.y] + r4.y] = s4.y;
    csr[rowoff[d4.z] + r4.z] = s4.z;
    csr[rowoff[d4.w] + r4.w] = s4.w;
}

// ---------------- fused: gather(bf16) + GEMM(fp32) + bias + LN + tanh --------
// Block 256 = 4 independent waves; each wave owns 4 rows. Lane owns cols
// (2*lane, 2*lane+1). Edge loop x4-unrolled for MLP; GEMM unroll capped at 4
// (full unroll spills: R4 postmortem, VGPR 256 + 2.5GB scratch traffic).
__global__ __launch_bounds__(256) void k_main(
        const int* __restrict__ rowoff, const int* __restrict__ csr,
        const float* __restrict__ dinv, const float* __restrict__ h,
        const unsigned* __restrict__ hb,
        const float* __restrict__ Wg,   const float* __restrict__ bias,
        const float* __restrict__ gamma,const float* __restrict__ beta,
        float* __restrict__ out) {
    int tid = threadIdx.x;
    int w = tid >> 6, lane = tid & 63;
    int rowBase = blockIdx.x * 16 + w * 4;
    const float2* h2 = (const float2*)h;
    const float2* W2 = (const float2*)Wg;

    // ---- gather into registers: x[r] = dn*(dn*h[row] + sum dinv[s]*hb[s]) ----
    float2 x[4];
    for (int r = 0; r < 4; r++) {
        int row = rowBase + r;
        float dn = dinv[row];
        float2 hv = h2[(size_t)row * 64 + lane];   // self-loop in fp32
        float2 a;
        a.x = dn * hv.x; a.y = dn * hv.y;
        int start = rowoff[row], end = rowoff[row + 1];
        for (int c = start; c < end; c += 64) {
            int m = end - c; if (m > 64) m = 64;
            int s = 0; float wv = 0.f;
            if (lane < m) { s = csr[c + lane]; wv = dinv[s]; }
            int j = 0;
            for (; j + 3 < m; j += 4) {
                int   sa = __shfl(s,  j, 64),     sb = __shfl(s,  j + 1, 64);
                int   sc = __shfl(s,  j + 2, 64), sd = __shfl(s,  j + 3, 64);
                float wa = __shfl(wv, j, 64),     wb = __shfl(wv, j + 1, 64);
                float wc = __shfl(wv, j + 2, 64), wd = __shfl(wv, j + 3, 64);
                unsigned pa = hb[(size_t)sa * 64 + lane];
                unsigned pb = hb[(size_t)sb * 64 + lane];
                unsigned pc = hb[(size_t)sc * 64 + lane];
                unsigned pd = hb[(size_t)sd * 64 + lane];
                a.x = fmaf(wa, __uint_as_float(pa << 16), a.x);
                a.y = fmaf(wa, __uint_as_float(pa & 0xFFFF0000u), a.y);
                a.x = fmaf(wb, __uint_as_float(pb << 16), a.x);
                a.y = fmaf(wb, __uint_as_float(pb & 0xFFFF0000u), a.y);
                a.x = fmaf(wc, __uint_as_float(pc << 16), a.x);
                a.y = fmaf(wc, __uint_as_float(pc & 0xFFFF0000u), a.y);
                a.x = fmaf(wd, __uint_as_float(pd << 16), a.x);
                a.y = fmaf(wd, __uint_as_float(pd & 0xFFFF0000u), a.y);
            }
            for (; j < m; j++) {
                int   sj = __shfl(s,  j, 64);
                float wj = __shfl(wv, j, 64);
                unsigned pj = hb[(size_t)sj * 64 + lane];
                a.x = fmaf(wj, __uint_as_float(pj << 16), a.x);
                a.y = fmaf(wj, __uint_as_float(pj & 0xFFFF0000u), a.y);
            }
        }
        a.x *= dn; a.y *= dn;
        x[r] = a;
    }

    // ---- GEMM via register broadcast: y[c] = sum_k x[k] * W[k][c] ----
    float2 acc[4];
#pragma unroll
    for (int r = 0; r < 4; r++) acc[r] = make_float2(0.f, 0.f);

#pragma unroll 4
    for (int j = 0; j < 64; j++) {            // even k = 2j (lane j's .x)
        float2 wv = W2[(size_t)(2 * j) * 64 + lane];
#pragma unroll
        for (int r = 0; r < 4; r++) {
            float xk = __shfl(x[r].x, j, 64);
            acc[r].x = fmaf(xk, wv.x, acc[r].x);
            acc[r].y = fmaf(xk, wv.y, acc[r].y);
        }
    }
#pragma unroll 4
    for (int j = 0; j < 64; j++) {            // odd k = 2j+1 (lane j's .y)
        float2 wv = W2[(size_t)(2 * j + 1) * 64 + lane];
#pragma unroll
        for (int r = 0; r < 4; r++) {
            float xk = __shfl(x[r].y, j, 64);
            acc[r].x = fmaf(xk, wv.x, acc[r].x);
            acc[r].y = fmaf(xk, wv.y, acc[r].y);
        }
    }

    // ---- bias + LN + tanh + store ----
    float2 bi = ((const float2*)bias)[lane];
    float2 ga = ((const float2*)gamma)[lane];
    float2 be = ((const float2*)beta)[lane];
#pragma unroll
    for (int r = 0; r < 4; r++) {
        int row = rowBase + r;
        float y0 = acc[r].x + bi.x;
        float y1 = acc[r].y + bi.y;
        float s = y0 + y1;
#pragma unroll
        for (int off = 32; off > 0; off >>= 1) s += __shfl_xor(s, off, 64);
        float m = s * (1.0f / 128.0f);
        float v0 = y0 - m, v1 = y1 - m;
        float vs = v0 * v0 + v1 * v1;
#pragma unroll
        for (int off = 32; off > 0; off >>= 1) vs += __shfl_xor(vs, off, 64);
        float rstd = rsqrtf(vs * (1.0f / 128.0f) + 1e-5f);
        float2 o;
        o.x = tanhf(v0 * rstd * ga.x + be.x);
        o.y = tanhf(v1 * rstd * ga.y + be.y);
        *(float2*)&out[(size_t)row * D + lane * 2] = o;
    }
}

extern "C" void kernel_launch(void* const* d_in, const int* in_sizes, int n_in,
                              void* d_out, int out_size, void* d_ws, size_t ws_size,
                              hipStream_t stream) {
    // inputs: t, h, edge_index, batch_size, W, b, gamma, beta
    const float* h     = (const float*)d_in[1];
    const int*   ei    = (const int*)  d_in[2];
    const float* Wg    = (const float*)d_in[4];
    const float* b     = (const float*)d_in[5];
    const float* gamma = (const float*)d_in[6];
    const float* beta  = (const float*)d_in[7];
    float* out = (float*)d_out;

    // workspace layout
    int*            deg    = (int*)d_ws;                      // NN ints
    unsigned short* rank   = (unsigned short*)(deg + NN);     // NE ushorts
    int*            rowoff = (int*)(rank + NE);               // NN+1 ints
    float*          dinv   = (float*)(rowoff + NN + 1);       // NN floats
    int*            partial= (int*)(dinv + NN);               // 64 ints
    int*            csr    = partial + 64;                    // NE ints
    unsigned*       hb     = (unsigned*)(csr + NE);           // NN*64 uints (12.8MB)

    hipMemsetAsync(deg, 0, NN * sizeof(int), stream);
    // zero tail outputs (zeros_like(edge_index) + zeros_like(batch_size))
    size_t dh_bytes  = (size_t)NN * D * sizeof(float);
    size_t out_bytes = (size_t)out_size * sizeof(float);
    if (out_bytes > dh_bytes)
        hipMemsetAsync((char*)d_out + dh_bytes, 0, out_bytes - dh_bytes, stream);

    k_deg   <<<625,   320, 0, stream>>>(ei, deg, rank);
    k_cvt   <<<12500, 256, 0, stream>>>(h, hb);
    k_scan_a<<<NSCAN, 256, 0, stream>>>(deg, partial, dinv);
    k_scan_c<<<NSCAN, 256, 0, stream>>>(deg, partial, rowoff);
    k_fill  <<<625,   320, 0, stream>>>(ei, rowoff, rank, csr);
    k_main  <<<NN / 16, 256, 0, stream>>>(rowoff, csr, dinv, h, hb, Wg, b, gamma, beta, out);
}